// Round 8
// baseline (480.710 us; speedup 1.0000x reference)
//
#include <hip/hip_runtime.h>
#include <hip/hip_bf16.h>
#include <cstdint>
#include <cstddef>

#define B_ 4
#define S_ 2048
#define D_ 1024
#define H_ 16
#define DK_ 64
#define NTOK (B_*S_)

typedef __bf16 bf16;
typedef __bf16 bf16x8 __attribute__((ext_vector_type(8)));
typedef short s16x4 __attribute__((ext_vector_type(4)));
typedef float f32x4 __attribute__((ext_vector_type(4)));

#define AS1 __attribute__((address_space(1)))
#define AS3 __attribute__((address_space(3)))

static __device__ __forceinline__ short f2bf_s(float f) {
    return __builtin_bit_cast(short, (__bf16)f);
}

static __device__ __forceinline__ f32x4 mfma16(s16x4 a, s16x4 b, f32x4 c) {
#if __has_builtin(__builtin_amdgcn_mfma_f32_16x16x16bf16_1k)
    return __builtin_amdgcn_mfma_f32_16x16x16bf16_1k(a, b, c, 0, 0, 0);
#else
    asm volatile("v_mfma_f32_16x16x16_bf16 %0, %1, %2, %0\n\ts_nop 7\n\ts_nop 7"
                 : "+v"(c) : "v"(a), "v"(b));
    return c;
#endif
}

// ---------------- fused fp32 -> bf16 convert: [X | Wq | Wk | Wv | Wo] ----------------
__global__ void cvt_all(const float* __restrict__ x, const float* __restrict__ wq,
                        const float* __restrict__ wk, const float* __restrict__ wv,
                        const float* __restrict__ wo, bf16* __restrict__ dst) {
    const int NX8 = NTOK * D_ / 8;
    const int W8 = D_ * D_ / 8;          // 131072 = 2^17
    int i = blockIdx.x * blockDim.x + threadIdx.x;
    if (i >= NX8 + 4 * W8) return;
    const float* src; int j;
    if (i < NX8) { src = x; j = i; }
    else {
        int k = i - NX8;
        int w = k >> 17;
        j = k & (W8 - 1);
        src = w == 0 ? wq : (w == 1 ? wk : (w == 2 ? wv : wo));
    }
    const float4* s4 = reinterpret_cast<const float4*>(src) + (size_t)j * 2;
    float4 a = s4[0], b = s4[1];
    bf16x8 o;
    o[0] = (bf16)a.x; o[1] = (bf16)a.y; o[2] = (bf16)a.z; o[3] = (bf16)a.w;
    o[4] = (bf16)b.x; o[5] = (bf16)b.y; o[6] = (bf16)b.z; o[7] = (bf16)b.w;
    reinterpret_cast<bf16x8*>(dst)[i] = o;
}

// ---------------- RoPE cos/sin table: [NTOK][32] float2 ----------------
__global__ void rope_table(const int* __restrict__ pos, float2* __restrict__ tab) {
    int i = blockIdx.x * blockDim.x + threadIdx.x;
    if (i >= NTOK * 32) return;
    int n = i >> 5, p = i & 31;
    float pf = (float)pos[n];
    float freq = powf(10000.0f, -(float)p * (1.0f / 32.0f));
    float ang = pf * freq;
    float s, c;
    sincosf(ang, &s, &c);
    tab[i] = make_float2(c, s);
}

// ---------------- 256x128 GEMM, counted-vmcnt pipeline (unchanged from R6) ----------------
template<int MODE>
__global__ __launch_bounds__(512, 2)
void gemm256(const bf16* __restrict__ A, const bf16* __restrict__ Bw,
             void* __restrict__ OutP, const float2* __restrict__ tab) {
    const float SCL2E = 0.125f * 1.44269504088896340736f;
    constexpr int NKT = 16;                       // K/64
    __shared__ alignas(16) bf16 lds[2][(256 + 128) * 64];
    const int tid = threadIdx.x;
    const int lane = tid & 63;
    const int wid = tid >> 6;
    const int wm = wid >> 2;                      // 0..1
    const int wn = wid & 3;                       // 0..3
    const int lr = lane & 15, lg = lane >> 4;
    const int m0 = blockIdx.x * 256;
    const int n0g = blockIdx.y * 128;             // global col (spans 3072 for QKV)

    f32x4 acc[8][2] = {};

    auto stage = [&](int kt, int bufi) {
        bf16* dst = &lds[bufi][0];
#pragma unroll
        for (int j = 0; j < 4; ++j) {
            int flat = j * 512 + tid;
            int r = flat >> 3, c = flat & 7;
            const bf16* src = A + (size_t)(m0 + r) * 1024 + kt * 64 + ((c ^ (r & 7)) << 3);
            __builtin_amdgcn_global_load_lds((const AS1 uint32_t*)src,
                                             (AS3 uint32_t*)(dst + (size_t)flat * 8), 16, 0, 0);
        }
#pragma unroll
        for (int j = 0; j < 2; ++j) {
            int f2 = j * 512 + tid;
            int r = f2 >> 3, c = f2 & 7;
            const bf16* src = Bw + (size_t)(n0g + r) * 1024 + kt * 64 + ((c ^ (r & 7)) << 3);
            __builtin_amdgcn_global_load_lds((const AS1 uint32_t*)src,
                                             (AS3 uint32_t*)(dst + 256 * 64 + (size_t)f2 * 8), 16, 0, 0);
        }
    };

    stage(0, 0);

    for (int kt = 0; kt < NKT; ++kt) {
        const bf16* bufA = &lds[kt & 1][0];
        const bf16* bufB = bufA + 256 * 64;

        asm volatile("" ::: "memory");
        __builtin_amdgcn_s_barrier();             // BAR-A: reads of buf[(kt+1)&1] done
        asm volatile("" ::: "memory");
        if (kt + 1 < NKT) {
            stage(kt + 1, (kt + 1) & 1);
            asm volatile("s_waitcnt vmcnt(6)" ::: "memory");
        } else {
            asm volatile("s_waitcnt vmcnt(0)" ::: "memory");
        }
        __builtin_amdgcn_s_barrier();             // BAR-B: buf[kt&1] valid
        asm volatile("" ::: "memory");

        const int sx = lr & 7;
        bf16x8 af[4][2], bfr[2][2];
#pragma unroll
        for (int mf = 0; mf < 4; ++mf)
#pragma unroll
            for (int kh = 0; kh < 2; ++kh)
                af[mf][kh] = *reinterpret_cast<const bf16x8*>(
                    &bufA[(wm * 128 + mf * 16 + lr) * 64 + (((kh * 4 + lg) ^ sx) << 3)]);
#pragma unroll
        for (int kh = 0; kh < 2; ++kh)
            bfr[0][kh] = *reinterpret_cast<const bf16x8*>(
                &bufB[(wn * 32 + lr) * 64 + (((kh * 4 + lg) ^ sx) << 3)]);
#pragma unroll
        for (int mf = 0; mf < 4; ++mf)
#pragma unroll
            for (int kh = 0; kh < 2; ++kh)
                acc[mf][0] = __builtin_amdgcn_mfma_f32_16x16x32_bf16(af[mf][kh], bfr[0][kh], acc[mf][0], 0, 0, 0);
#pragma unroll
        for (int kh = 0; kh < 2; ++kh)
            bfr[1][kh] = *reinterpret_cast<const bf16x8*>(
                &bufB[(wn * 32 + 16 + lr) * 64 + (((kh * 4 + lg) ^ sx) << 3)]);
#pragma unroll
        for (int mf = 0; mf < 4; ++mf)
#pragma unroll
            for (int kh = 0; kh < 2; ++kh)
                acc[mf][1] = __builtin_amdgcn_mfma_f32_16x16x32_bf16(af[mf][kh], bfr[1][kh], acc[mf][1], 0, 0, 0);
#pragma unroll
        for (int mf = 0; mf < 4; ++mf)
#pragma unroll
            for (int kh = 0; kh < 2; ++kh)
                af[mf][kh] = *reinterpret_cast<const bf16x8*>(
                    &bufA[(wm * 128 + 64 + mf * 16 + lr) * 64 + (((kh * 4 + lg) ^ sx) << 3)]);
#pragma unroll
        for (int mf = 0; mf < 4; ++mf)
#pragma unroll
            for (int kh = 0; kh < 2; ++kh)
                acc[4 + mf][0] = __builtin_amdgcn_mfma_f32_16x16x32_bf16(af[mf][kh], bfr[0][kh], acc[4 + mf][0], 0, 0, 0);
#pragma unroll
        for (int mf = 0; mf < 4; ++mf)
#pragma unroll
            for (int kh = 0; kh < 2; ++kh)
                acc[4 + mf][1] = __builtin_amdgcn_mfma_f32_16x16x32_bf16(af[mf][kh], bfr[1][kh], acc[4 + mf][1], 0, 0, 0);
    }

#pragma unroll
    for (int mf = 0; mf < 8; ++mf) {
#pragma unroll
        for (int nf = 0; nf < 2; ++nf) {
#pragma unroll
            for (int r = 0; r < 4; ++r) {
                int row = m0 + wm * 128 + mf * 16 + lg * 4 + r;
                int colg = n0g + wn * 32 + nf * 16 + lr;
                float v = acc[mf][nf][r];
                if (MODE == 2) {
                    ((float*)OutP)[(size_t)row * 1024 + colg] = v;
                } else {
                    int which = colg >> 10;
                    int col = colg & 1023;
                    bf16* O = (bf16*)OutP + (size_t)which * NTOK * D_;
                    if (which < 2) {
                        float partner = __shfl_xor(v, 1, 64);
                        float2 cs = tab[(size_t)row * 32 + ((col >> 1) & 31)];
                        float o = (col & 1) ? fmaf(v, cs.x, partner * cs.y)
                                            : fmaf(v, cs.x, -partner * cs.y);
                        if (which == 0) o *= SCL2E;
                        O[(size_t)row * D_ + col] = (bf16)o;
                    } else {
                        O[(size_t)row * D_ + col] = (bf16)v;
                    }
                }
            }
        }
    }
}

// ---------------- causal flash attention: 12 balanced bins, 3 blocks/CU ----------------
// grid (12, 64), 256 thr = 4 waves. Bin table (LPT): bx0-7 single strip qt=15-bx
// (work 32..18); bx8-11 pairs (7,0),(6,1),(5,2),(4,3) (work 18). 768 blocks =
// exactly 3/CU at launch_bounds(256,3): VGPR cap ~170 > 124 needed -> NO spill
// (R7 lesson: occupancy via grid shape, never via register squeeze).
// Per-tile math byte-identical to R6's verified kernel.
__global__ __launch_bounds__(256, 3)
void flash_attn7(const bf16* __restrict__ Q, const bf16* __restrict__ Kr,
                 const bf16* __restrict__ V, bf16* __restrict__ O) {
    __shared__ bf16 Ks[2][64 * 64];
    __shared__ bf16 Vt[2][64 * 64];
    const int tid = threadIdx.x, lane = tid & 63, w = tid >> 6;
    const int lr = lane & 15, lg = lane >> 4;
    const int bx = blockIdx.x;
    int qA, qB, nt1;
    if (bx < 8) { qA = 15 - bx; qB = qA;      nt1 = 0; }            // single strip
    else        { qA = 7 - (bx - 8); qB = bx - 8; nt1 = 2 * qB + 2; } // pair
    const int q0[2] = { qA * 128, qB * 128 };
    const int ntS[2] = { 2 * qA + 2, nt1 };
    const int NT = ntS[0];
    const int bh = blockIdx.y;
    const int b = bh >> 4, h = bh & 15;
    const size_t base = ((size_t)b * S_) * D_ + (size_t)h * DK_;

    // Q fragments (B operand of swapped QK): col=lane&15=q, k=lg*8 (+32)
    bf16x8 aq[2][2][2];
#pragma unroll
    for (int si = 0; si < 2; ++si)
#pragma unroll
        for (int qs = 0; qs < 2; ++qs) {
            int qrow = q0[si] + w * 32 + qs * 16 + lr;
            const bf16* qp = Q + base + (size_t)qrow * D_ + lg * 8;
            aq[si][qs][0] = *reinterpret_cast<const bf16x8*>(qp);
            aq[si][qs][1] = *reinterpret_cast<const bf16x8*>(qp + 32);
        }

    f32x4 acc[2][2][4] = {};
    float m_run[2][2] = {{-1e30f, -1e30f}, {-1e30f, -1e30f}};
    float l_run[2][2] = {{0.f, 0.f}, {0.f, 0.f}};

    const int sjj = tid >> 3;
    const int se0 = (tid & 7) * 8;
    const int vx = tid & 7;
    bf16x8 kreg[2], vreg[2];
#pragma unroll
    for (int i = 0; i < 2; ++i) {
        int row = sjj + i * 32;
        kreg[i] = *reinterpret_cast<const bf16x8*>(&Kr[base + (size_t)row * D_ + se0]);
        vreg[i] = *reinterpret_cast<const bf16x8*>(&V [base + (size_t)row * D_ + se0]);
    }

    for (int t = 0; t < NT; ++t) {
        const int j0 = t * 64;
        bf16* KsB = Ks[t & 1];
        bf16* VtB = Vt[t & 1];
#pragma unroll
        for (int i = 0; i < 2; ++i) {
            int jj = sjj + i * 32;
            *reinterpret_cast<bf16x8*>(&KsB[jj * 64 + (se0 ^ ((jj & 7) << 3))]) = kreg[i];
#pragma unroll
            for (int q = 0; q < 8; ++q) {
                int dd = se0 + q;
                int vswz = ((q ^ vx) & 7) << 3;
                VtB[dd * 64 + (jj ^ vswz)] = vreg[i][q];
            }
        }
        if (t + 1 < NT) {
#pragma unroll
            for (int i = 0; i < 2; ++i) {
                int row = (t + 1) * 64 + sjj + i * 32;
                kreg[i] = *reinterpret_cast<const bf16x8*>(&Kr[base + (size_t)row * D_ + se0]);
                vreg[i] = *reinterpret_cast<const bf16x8*>(&V [base + (size_t)row * D_ + se0]);
            }
        }
        __syncthreads();

#pragma unroll
        for (int si = 0; si < 2; ++si) {
            if (t >= ntS[si]) continue;
            const int qmaxw = q0[si] + w * 32 + 31;
            if (j0 > qmaxw) continue;

            f32x4 sc[2][4];
            __builtin_amdgcn_s_setprio(1);
#pragma unroll
            for (int nt = 0; nt < 4; ++nt) {
                int krow = nt * 16 + lr;
                int swz = (krow & 7) << 3;
                bf16x8 a0 = *reinterpret_cast<const bf16x8*>(&KsB[krow * 64 + ((lg * 8) ^ swz)]);
                bf16x8 a1 = *reinterpret_cast<const bf16x8*>(&KsB[krow * 64 + ((32 + lg * 8) ^ swz)]);
#pragma unroll
                for (int qs = 0; qs < 2; ++qs) {
                    f32x4 tv = {};
                    tv = __builtin_amdgcn_mfma_f32_16x16x32_bf16(a0, aq[si][qs][0], tv, 0, 0, 0);
                    tv = __builtin_amdgcn_mfma_f32_16x16x32_bf16(a1, aq[si][qs][1], tv, 0, 0, 0);
                    sc[qs][nt] = tv;
                }
            }
            __builtin_amdgcn_s_setprio(0);

            s16x4 ap[2][4];
#pragma unroll
            for (int qs = 0; qs < 2; ++qs) {
                const int qrow = q0[si] + w * 32 + qs * 16 + lr;
                if (j0 + 63 > q0[si] + w * 32 + qs * 16) {
#pragma unroll
                    for (int nt = 0; nt < 4; ++nt)
#pragma unroll
                        for (int r = 0; r < 4; ++r) {
                            int kv = j0 + nt * 16 + lg * 4 + r;
                            if (kv > qrow) sc[qs][nt][r] = -1e30f;
                        }
                }
                float tmax = sc[qs][0][0];
#pragma unroll
                for (int nt = 0; nt < 4; ++nt)
#pragma unroll
                    for (int r = 0; r < 4; ++r) tmax = fmaxf(tmax, sc[qs][nt][r]);
                tmax = fmaxf(tmax, __shfl_xor(tmax, 16, 64));
                tmax = fmaxf(tmax, __shfl_xor(tmax, 32, 64));
                float mold = m_run[si][qs];
                if (!__all(tmax - mold <= 8.0f)) {
                    float mnew = fmaxf(mold, tmax);
                    float corr = exp2f(mold - mnew);
                    m_run[si][qs] = mnew;
                    l_run[si][qs] *= corr;
#pragma unroll
                    for (int r = 0; r < 4; ++r) {
                        float cr = __shfl(corr, (lane & 48) | (lg * 4 + r), 64);
#pragma unroll
                        for (int dt = 0; dt < 4; ++dt) acc[si][qs][dt][r] *= cr;
                    }
                }
                float mnow = m_run[si][qs];
                float rs = 0.f;
#pragma unroll
                for (int nt = 0; nt < 4; ++nt)
#pragma unroll
                    for (int r = 0; r < 4; ++r) {
                        float p = exp2f(sc[qs][nt][r] - mnow);
                        rs += p;
                        ap[qs][nt][r] = f2bf_s(p);
                    }
                rs += __shfl_xor(rs, 16, 64);
                rs += __shfl_xor(rs, 32, 64);
                l_run[si][qs] += rs;
            }

            __builtin_amdgcn_s_setprio(1);
#pragma unroll
            for (int dt = 0; dt < 4; ++dt) {
                int vrow = dt * 16 + lr;
                int vswz = (((vrow & 7) ^ (vrow >> 3)) & 7) << 3;
                s16x4 bv[4];
#pragma unroll
                for (int nt = 0; nt < 4; ++nt)
                    bv[nt] = *reinterpret_cast<const s16x4*>(&VtB[vrow * 64 + ((nt * 16 + lg * 4) ^ vswz)]);
#pragma unroll
                for (int qs = 0; qs < 2; ++qs)
#pragma unroll
                    for (int nt = 0; nt < 4; ++nt)
                        acc[si][qs][dt] = mfma16(ap[qs][nt], bv[nt], acc[si][qs][dt]);
            }
            __builtin_amdgcn_s_setprio(0);
        }
    }

    // epilogue: skip si=1 on single-strip blocks (ntS[1]==0 -> l_run=0, rcp(0) garbage)
#pragma unroll
    for (int si = 0; si < 2; ++si) {
        if (si == 1 && ntS[1] == 0) continue;
#pragma unroll
        for (int qs = 0; qs < 2; ++qs) {
            float inv = __builtin_amdgcn_rcpf(l_run[si][qs]);
#pragma unroll
            for (int r = 0; r < 4; ++r) {
                float invr = __shfl(inv, (lane & 48) | (lg * 4 + r), 64);
                int row = q0[si] + w * 32 + qs * 16 + lg * 4 + r;
#pragma unroll
                for (int dt = 0; dt < 4; ++dt)
                    O[base + (size_t)row * D_ + dt * 16 + lr] = (bf16)(acc[si][qs][dt][r] * invr);
            }
        }
    }
}

// ---------------- launcher ----------------
extern "C" void kernel_launch(void* const* d_in, const int* in_sizes, int n_in,
                              void* d_out, int out_size, void* d_ws, size_t ws_size,
                              hipStream_t stream) {
    const float* x  = (const float*)d_in[0];
    const int*   tp = (const int*)d_in[1];
    const float* wq = (const float*)d_in[2];
    const float* wk = (const float*)d_in[3];
    const float* wv = (const float*)d_in[4];
    const float* wo = (const float*)d_in[5];

    bf16* ws = (bf16*)d_ws;
    bf16* Xbf = ws;
    bf16* Wqb = Xbf + (size_t)NTOK * D_;          // [3072][1024] packed Wq|Wk|Wv
    bf16* Wkb = Wqb + (size_t)D_ * D_;
    bf16* Wvb = Wkb + (size_t)D_ * D_;
    bf16* Wob = Wvb + (size_t)D_ * D_;
    bf16* Qr  = Wob + (size_t)D_ * D_;
    bf16* Kb  = Qr + (size_t)NTOK * D_;
    bf16* Vb  = Kb + (size_t)NTOK * D_;
    bf16* AO  = Vb + (size_t)NTOK * D_;
    float2* tab = (float2*)(AO + (size_t)NTOK * D_);
    (void)ws_size; (void)in_sizes; (void)n_in; (void)out_size;
    (void)Wkb; (void)Wvb;

    {
        int ntot8 = (NTOK * D_ + 4 * D_ * D_) / 8;
        cvt_all<<<(ntot8 + 255) / 256, 256, 0, stream>>>(x, wq, wk, wv, wo, Xbf);
    }
    rope_table<<<(NTOK * 32 + 255) / 256, 256, 0, stream>>>(tp, tab);

    // QKV: one GEMM vs packed [3072][1024] weights; grid 32x24 = 768 blocks
    gemm256<1><<<dim3(NTOK / 256, 24), 512, 0, stream>>>(Xbf, Wqb, Qr, tab);

    flash_attn7<<<dim3(12, B_ * H_), 256, 0, stream>>>(Qr, Kb, Vb, AO);

    // out-projection: grid 32x8 = 256 blocks, fp32 out
    gemm256<2><<<dim3(NTOK / 256, D_ / 128), 512, 0, stream>>>(AO, Wob, d_out, nullptr);
}

// Round 9
// 252.740 us; speedup vs baseline: 1.9020x; 1.9020x over previous
//
#include <hip/hip_runtime.h>
#include <hip/hip_bf16.h>
#include <cstdint>
#include <cstddef>

#define B_ 4
#define S_ 2048
#define D_ 1024
#define H_ 16
#define DK_ 64
#define NTOK (B_*S_)

typedef __bf16 bf16;
typedef __bf16 bf16x8 __attribute__((ext_vector_type(8)));
typedef short s16x4 __attribute__((ext_vector_type(4)));
typedef float f32x4 __attribute__((ext_vector_type(4)));

#define AS1 __attribute__((address_space(1)))
#define AS3 __attribute__((address_space(3)))

static __device__ __forceinline__ short f2bf_s(float f) {
    return __builtin_bit_cast(short, (__bf16)f);
}

static __device__ __forceinline__ f32x4 mfma16(s16x4 a, s16x4 b, f32x4 c) {
#if __has_builtin(__builtin_amdgcn_mfma_f32_16x16x16bf16_1k)
    return __builtin_amdgcn_mfma_f32_16x16x16bf16_1k(a, b, c, 0, 0, 0);
#else
    asm volatile("v_mfma_f32_16x16x16_bf16 %0, %1, %2, %0\n\ts_nop 7\n\ts_nop 7"
                 : "+v"(c) : "v"(a), "v"(b));
    return c;
#endif
}

// ---------------- fused fp32 -> bf16 convert: [X | Wq | Wk | Wv | Wo] ----------------
__global__ void cvt_all(const float* __restrict__ x, const float* __restrict__ wq,
                        const float* __restrict__ wk, const float* __restrict__ wv,
                        const float* __restrict__ wo, bf16* __restrict__ dst) {
    const int NX8 = NTOK * D_ / 8;
    const int W8 = D_ * D_ / 8;          // 131072 = 2^17
    int i = blockIdx.x * blockDim.x + threadIdx.x;
    if (i >= NX8 + 4 * W8) return;
    const float* src; int j;
    if (i < NX8) { src = x; j = i; }
    else {
        int k = i - NX8;
        int w = k >> 17;
        j = k & (W8 - 1);
        src = w == 0 ? wq : (w == 1 ? wk : (w == 2 ? wv : wo));
    }
    const float4* s4 = reinterpret_cast<const float4*>(src) + (size_t)j * 2;
    float4 a = s4[0], b = s4[1];
    bf16x8 o;
    o[0] = (bf16)a.x; o[1] = (bf16)a.y; o[2] = (bf16)a.z; o[3] = (bf16)a.w;
    o[4] = (bf16)b.x; o[5] = (bf16)b.y; o[6] = (bf16)b.z; o[7] = (bf16)b.w;
    reinterpret_cast<bf16x8*>(dst)[i] = o;
}

// ---------------- RoPE cos/sin table: [NTOK][32] float2 ----------------
__global__ void rope_table(const int* __restrict__ pos, float2* __restrict__ tab) {
    int i = blockIdx.x * blockDim.x + threadIdx.x;
    if (i >= NTOK * 32) return;
    int n = i >> 5, p = i & 31;
    float pf = (float)pos[n];
    float freq = powf(10000.0f, -(float)p * (1.0f / 32.0f));
    float ang = pf * freq;
    float s, c;
    sincosf(ang, &s, &c);
    tab[i] = make_float2(c, s);
}

// ---------------- 256x128 GEMM, counted-vmcnt pipeline (unchanged from R6) ----------------
template<int MODE>
__global__ __launch_bounds__(512, 2)
void gemm256(const bf16* __restrict__ A, const bf16* __restrict__ Bw,
             void* __restrict__ OutP, const float2* __restrict__ tab) {
    const float SCL2E = 0.125f * 1.44269504088896340736f;
    constexpr int NKT = 16;                       // K/64
    __shared__ alignas(16) bf16 lds[2][(256 + 128) * 64];
    const int tid = threadIdx.x;
    const int lane = tid & 63;
    const int wid = tid >> 6;
    const int wm = wid >> 2;                      // 0..1
    const int wn = wid & 3;                       // 0..3
    const int lr = lane & 15, lg = lane >> 4;
    const int m0 = blockIdx.x * 256;
    const int n0g = blockIdx.y * 128;             // global col (spans 3072 for QKV)

    f32x4 acc[8][2] = {};

    auto stage = [&](int kt, int bufi) {
        bf16* dst = &lds[bufi][0];
#pragma unroll
        for (int j = 0; j < 4; ++j) {
            int flat = j * 512 + tid;
            int r = flat >> 3, c = flat & 7;
            const bf16* src = A + (size_t)(m0 + r) * 1024 + kt * 64 + ((c ^ (r & 7)) << 3);
            __builtin_amdgcn_global_load_lds((const AS1 uint32_t*)src,
                                             (AS3 uint32_t*)(dst + (size_t)flat * 8), 16, 0, 0);
        }
#pragma unroll
        for (int j = 0; j < 2; ++j) {
            int f2 = j * 512 + tid;
            int r = f2 >> 3, c = f2 & 7;
            const bf16* src = Bw + (size_t)(n0g + r) * 1024 + kt * 64 + ((c ^ (r & 7)) << 3);
            __builtin_amdgcn_global_load_lds((const AS1 uint32_t*)src,
                                             (AS3 uint32_t*)(dst + 256 * 64 + (size_t)f2 * 8), 16, 0, 0);
        }
    };

    stage(0, 0);

    for (int kt = 0; kt < NKT; ++kt) {
        const bf16* bufA = &lds[kt & 1][0];
        const bf16* bufB = bufA + 256 * 64;

        asm volatile("" ::: "memory");
        __builtin_amdgcn_s_barrier();             // BAR-A: reads of buf[(kt+1)&1] done
        asm volatile("" ::: "memory");
        if (kt + 1 < NKT) {
            stage(kt + 1, (kt + 1) & 1);
            asm volatile("s_waitcnt vmcnt(6)" ::: "memory");
        } else {
            asm volatile("s_waitcnt vmcnt(0)" ::: "memory");
        }
        __builtin_amdgcn_s_barrier();             // BAR-B: buf[kt&1] valid
        asm volatile("" ::: "memory");

        const int sx = lr & 7;
        bf16x8 af[4][2], bfr[2][2];
#pragma unroll
        for (int mf = 0; mf < 4; ++mf)
#pragma unroll
            for (int kh = 0; kh < 2; ++kh)
                af[mf][kh] = *reinterpret_cast<const bf16x8*>(
                    &bufA[(wm * 128 + mf * 16 + lr) * 64 + (((kh * 4 + lg) ^ sx) << 3)]);
#pragma unroll
        for (int kh = 0; kh < 2; ++kh)
            bfr[0][kh] = *reinterpret_cast<const bf16x8*>(
                &bufB[(wn * 32 + lr) * 64 + (((kh * 4 + lg) ^ sx) << 3)]);
#pragma unroll
        for (int mf = 0; mf < 4; ++mf)
#pragma unroll
            for (int kh = 0; kh < 2; ++kh)
                acc[mf][0] = __builtin_amdgcn_mfma_f32_16x16x32_bf16(af[mf][kh], bfr[0][kh], acc[mf][0], 0, 0, 0);
#pragma unroll
        for (int kh = 0; kh < 2; ++kh)
            bfr[1][kh] = *reinterpret_cast<const bf16x8*>(
                &bufB[(wn * 32 + 16 + lr) * 64 + (((kh * 4 + lg) ^ sx) << 3)]);
#pragma unroll
        for (int mf = 0; mf < 4; ++mf)
#pragma unroll
            for (int kh = 0; kh < 2; ++kh)
                acc[mf][1] = __builtin_amdgcn_mfma_f32_16x16x32_bf16(af[mf][kh], bfr[1][kh], acc[mf][1], 0, 0, 0);
#pragma unroll
        for (int mf = 0; mf < 4; ++mf)
#pragma unroll
            for (int kh = 0; kh < 2; ++kh)
                af[mf][kh] = *reinterpret_cast<const bf16x8*>(
                    &bufA[(wm * 128 + 64 + mf * 16 + lr) * 64 + (((kh * 4 + lg) ^ sx) << 3)]);
#pragma unroll
        for (int mf = 0; mf < 4; ++mf)
#pragma unroll
            for (int kh = 0; kh < 2; ++kh)
                acc[4 + mf][0] = __builtin_amdgcn_mfma_f32_16x16x32_bf16(af[mf][kh], bfr[0][kh], acc[4 + mf][0], 0, 0, 0);
#pragma unroll
        for (int mf = 0; mf < 4; ++mf)
#pragma unroll
            for (int kh = 0; kh < 2; ++kh)
                acc[4 + mf][1] = __builtin_amdgcn_mfma_f32_16x16x32_bf16(af[mf][kh], bfr[1][kh], acc[4 + mf][1], 0, 0, 0);
    }

#pragma unroll
    for (int mf = 0; mf < 8; ++mf) {
#pragma unroll
        for (int nf = 0; nf < 2; ++nf) {
#pragma unroll
            for (int r = 0; r < 4; ++r) {
                int row = m0 + wm * 128 + mf * 16 + lg * 4 + r;
                int colg = n0g + wn * 32 + nf * 16 + lr;
                float v = acc[mf][nf][r];
                if (MODE == 2) {
                    ((float*)OutP)[(size_t)row * 1024 + colg] = v;
                } else {
                    int which = colg >> 10;
                    int col = colg & 1023;
                    bf16* O = (bf16*)OutP + (size_t)which * NTOK * D_;
                    if (which < 2) {
                        float partner = __shfl_xor(v, 1, 64);
                        float2 cs = tab[(size_t)row * 32 + ((col >> 1) & 31)];
                        float o = (col & 1) ? fmaf(v, cs.x, partner * cs.y)
                                            : fmaf(v, cs.x, -partner * cs.y);
                        if (which == 0) o *= SCL2E;
                        O[(size_t)row * D_ + col] = (bf16)o;
                    } else {
                        O[(size_t)row * D_ + col] = (bf16)v;
                    }
                }
            }
        }
    }
}

// ---------------- causal flash attention: 12 balanced bins ----------------
// grid (12, 64), 256 thr = 4 waves. Bin table (LPT): bx0-7 single strip qt=15-bx
// (work 32..18); bx8-11 pairs (7,0),(6,1),(5,2),(4,3) (work 18). 768 blocks.
// launch_bounds(256,2) ONLY: R7/R8 lesson — min-waves>=3 triggers the gfx950
// arch-VGPR/AGPR budget split (84/64 regs -> mass spill). At (256,2) compiler
// uses ~128 VGPR (verified R3/R5); HW then fits 3 blocks/CU on its own
// (floor(512/128)=4 waves/SIMD, LDS 3x32KB<160KB).
__global__ __launch_bounds__(256, 2)
void flash_attn7(const bf16* __restrict__ Q, const bf16* __restrict__ Kr,
                 const bf16* __restrict__ V, bf16* __restrict__ O) {
    __shared__ bf16 Ks[2][64 * 64];
    __shared__ bf16 Vt[2][64 * 64];
    const int tid = threadIdx.x, lane = tid & 63, w = tid >> 6;
    const int lr = lane & 15, lg = lane >> 4;
    const int bx = blockIdx.x;
    int qA, qB, nt1;
    if (bx < 8) { qA = 15 - bx; qB = qA;      nt1 = 0; }            // single strip
    else        { qA = 7 - (bx - 8); qB = bx - 8; nt1 = 2 * qB + 2; } // pair
    const int q0[2] = { qA * 128, qB * 128 };
    const int ntS[2] = { 2 * qA + 2, nt1 };
    const int NT = ntS[0];
    const int bh = blockIdx.y;
    const int b = bh >> 4, h = bh & 15;
    const size_t base = ((size_t)b * S_) * D_ + (size_t)h * DK_;

    // Q fragments (B operand of swapped QK): col=lane&15=q, k=lg*8 (+32)
    bf16x8 aq[2][2][2];
#pragma unroll
    for (int si = 0; si < 2; ++si)
#pragma unroll
        for (int qs = 0; qs < 2; ++qs) {
            int qrow = q0[si] + w * 32 + qs * 16 + lr;
            const bf16* qp = Q + base + (size_t)qrow * D_ + lg * 8;
            aq[si][qs][0] = *reinterpret_cast<const bf16x8*>(qp);
            aq[si][qs][1] = *reinterpret_cast<const bf16x8*>(qp + 32);
        }

    f32x4 acc[2][2][4] = {};
    float m_run[2][2] = {{-1e30f, -1e30f}, {-1e30f, -1e30f}};
    float l_run[2][2] = {{0.f, 0.f}, {0.f, 0.f}};

    const int sjj = tid >> 3;
    const int se0 = (tid & 7) * 8;
    const int vx = tid & 7;
    bf16x8 kreg[2], vreg[2];
#pragma unroll
    for (int i = 0; i < 2; ++i) {
        int row = sjj + i * 32;
        kreg[i] = *reinterpret_cast<const bf16x8*>(&Kr[base + (size_t)row * D_ + se0]);
        vreg[i] = *reinterpret_cast<const bf16x8*>(&V [base + (size_t)row * D_ + se0]);
    }

    for (int t = 0; t < NT; ++t) {
        const int j0 = t * 64;
        bf16* KsB = Ks[t & 1];
        bf16* VtB = Vt[t & 1];
#pragma unroll
        for (int i = 0; i < 2; ++i) {
            int jj = sjj + i * 32;
            *reinterpret_cast<bf16x8*>(&KsB[jj * 64 + (se0 ^ ((jj & 7) << 3))]) = kreg[i];
#pragma unroll
            for (int q = 0; q < 8; ++q) {
                int dd = se0 + q;
                int vswz = ((q ^ vx) & 7) << 3;
                VtB[dd * 64 + (jj ^ vswz)] = vreg[i][q];
            }
        }
        if (t + 1 < NT) {
#pragma unroll
            for (int i = 0; i < 2; ++i) {
                int row = (t + 1) * 64 + sjj + i * 32;
                kreg[i] = *reinterpret_cast<const bf16x8*>(&Kr[base + (size_t)row * D_ + se0]);
                vreg[i] = *reinterpret_cast<const bf16x8*>(&V [base + (size_t)row * D_ + se0]);
            }
        }
        __syncthreads();

#pragma unroll
        for (int si = 0; si < 2; ++si) {
            if (t >= ntS[si]) continue;
            const int qmaxw = q0[si] + w * 32 + 31;
            if (j0 > qmaxw) continue;

            f32x4 sc[2][4];
            __builtin_amdgcn_s_setprio(1);
#pragma unroll
            for (int nt = 0; nt < 4; ++nt) {
                int krow = nt * 16 + lr;
                int swz = (krow & 7) << 3;
                bf16x8 a0 = *reinterpret_cast<const bf16x8*>(&KsB[krow * 64 + ((lg * 8) ^ swz)]);
                bf16x8 a1 = *reinterpret_cast<const bf16x8*>(&KsB[krow * 64 + ((32 + lg * 8) ^ swz)]);
#pragma unroll
                for (int qs = 0; qs < 2; ++qs) {
                    f32x4 tv = {};
                    tv = __builtin_amdgcn_mfma_f32_16x16x32_bf16(a0, aq[si][qs][0], tv, 0, 0, 0);
                    tv = __builtin_amdgcn_mfma_f32_16x16x32_bf16(a1, aq[si][qs][1], tv, 0, 0, 0);
                    sc[qs][nt] = tv;
                }
            }
            __builtin_amdgcn_s_setprio(0);

            s16x4 ap[2][4];
#pragma unroll
            for (int qs = 0; qs < 2; ++qs) {
                const int qrow = q0[si] + w * 32 + qs * 16 + lr;
                if (j0 + 63 > q0[si] + w * 32 + qs * 16) {
#pragma unroll
                    for (int nt = 0; nt < 4; ++nt)
#pragma unroll
                        for (int r = 0; r < 4; ++r) {
                            int kv = j0 + nt * 16 + lg * 4 + r;
                            if (kv > qrow) sc[qs][nt][r] = -1e30f;
                        }
                }
                float tmax = sc[qs][0][0];
#pragma unroll
                for (int nt = 0; nt < 4; ++nt)
#pragma unroll
                    for (int r = 0; r < 4; ++r) tmax = fmaxf(tmax, sc[qs][nt][r]);
                tmax = fmaxf(tmax, __shfl_xor(tmax, 16, 64));
                tmax = fmaxf(tmax, __shfl_xor(tmax, 32, 64));
                float mold = m_run[si][qs];
                if (!__all(tmax - mold <= 8.0f)) {
                    float mnew = fmaxf(mold, tmax);
                    float corr = exp2f(mold - mnew);
                    m_run[si][qs] = mnew;
                    l_run[si][qs] *= corr;
#pragma unroll
                    for (int r = 0; r < 4; ++r) {
                        float cr = __shfl(corr, (lane & 48) | (lg * 4 + r), 64);
#pragma unroll
                        for (int dt = 0; dt < 4; ++dt) acc[si][qs][dt][r] *= cr;
                    }
                }
                float mnow = m_run[si][qs];
                float rs = 0.f;
#pragma unroll
                for (int nt = 0; nt < 4; ++nt)
#pragma unroll
                    for (int r = 0; r < 4; ++r) {
                        float p = exp2f(sc[qs][nt][r] - mnow);
                        rs += p;
                        ap[qs][nt][r] = f2bf_s(p);
                    }
                rs += __shfl_xor(rs, 16, 64);
                rs += __shfl_xor(rs, 32, 64);
                l_run[si][qs] += rs;
            }

            __builtin_amdgcn_s_setprio(1);
#pragma unroll
            for (int dt = 0; dt < 4; ++dt) {
                int vrow = dt * 16 + lr;
                int vswz = (((vrow & 7) ^ (vrow >> 3)) & 7) << 3;
                s16x4 bv[4];
#pragma unroll
                for (int nt = 0; nt < 4; ++nt)
                    bv[nt] = *reinterpret_cast<const s16x4*>(&VtB[vrow * 64 + ((nt * 16 + lg * 4) ^ vswz)]);
#pragma unroll
                for (int qs = 0; qs < 2; ++qs)
#pragma unroll
                    for (int nt = 0; nt < 4; ++nt)
                        acc[si][qs][dt] = mfma16(ap[qs][nt], bv[nt], acc[si][qs][dt]);
            }
            __builtin_amdgcn_s_setprio(0);
        }
    }

    // epilogue: skip si=1 on single-strip blocks (ntS[1]==0 -> l_run=0, rcp(0) garbage)
#pragma unroll
    for (int si = 0; si < 2; ++si) {
        if (si == 1 && ntS[1] == 0) continue;
#pragma unroll
        for (int qs = 0; qs < 2; ++qs) {
            float inv = __builtin_amdgcn_rcpf(l_run[si][qs]);
#pragma unroll
            for (int r = 0; r < 4; ++r) {
                float invr = __shfl(inv, (lane & 48) | (lg * 4 + r), 64);
                int row = q0[si] + w * 32 + qs * 16 + lg * 4 + r;
#pragma unroll
                for (int dt = 0; dt < 4; ++dt)
                    O[base + (size_t)row * D_ + dt * 16 + lr] = (bf16)(acc[si][qs][dt][r] * invr);
            }
        }
    }
}

// ---------------- launcher ----------------
extern "C" void kernel_launch(void* const* d_in, const int* in_sizes, int n_in,
                              void* d_out, int out_size, void* d_ws, size_t ws_size,
                              hipStream_t stream) {
    const float* x  = (const float*)d_in[0];
    const int*   tp = (const int*)d_in[1];
    const float* wq = (const float*)d_in[2];
    const float* wk = (const float*)d_in[3];
    const float* wv = (const float*)d_in[4];
    const float* wo = (const float*)d_in[5];

    bf16* ws = (bf16*)d_ws;
    bf16* Xbf = ws;
    bf16* Wqb = Xbf + (size_t)NTOK * D_;          // [3072][1024] packed Wq|Wk|Wv
    bf16* Wkb = Wqb + (size_t)D_ * D_;
    bf16* Wvb = Wkb + (size_t)D_ * D_;
    bf16* Wob = Wvb + (size_t)D_ * D_;
    bf16* Qr  = Wob + (size_t)D_ * D_;
    bf16* Kb  = Qr + (size_t)NTOK * D_;
    bf16* Vb  = Kb + (size_t)NTOK * D_;
    bf16* AO  = Vb + (size_t)NTOK * D_;
    float2* tab = (float2*)(AO + (size_t)NTOK * D_);
    (void)ws_size; (void)in_sizes; (void)n_in; (void)out_size;
    (void)Wkb; (void)Wvb;

    {
        int ntot8 = (NTOK * D_ + 4 * D_ * D_) / 8;
        cvt_all<<<(ntot8 + 255) / 256, 256, 0, stream>>>(x, wq, wk, wv, wo, Xbf);
    }
    rope_table<<<(NTOK * 32 + 255) / 256, 256, 0, stream>>>(tp, tab);

    // QKV: one GEMM vs packed [3072][1024] weights; grid 32x24 = 768 blocks
    gemm256<1><<<dim3(NTOK / 256, 24), 512, 0, stream>>>(Xbf, Wqb, Qr, tab);

    flash_attn7<<<dim3(12, B_ * H_), 256, 0, stream>>>(Qr, Kb, Vb, AO);

    // out-projection: grid 32x8 = 256 blocks, fp32 out
    gemm256<2><<<dim3(NTOK / 256, D_ / 128), 512, 0, stream>>>(AO, Wob, d_out, nullptr);
}

// Round 10
// 206.287 us; speedup vs baseline: 2.3303x; 1.2252x over previous
//
#include <hip/hip_runtime.h>
#include <hip/hip_bf16.h>
#include <cstdint>
#include <cstddef>

#define B_ 4
#define S_ 2048
#define D_ 1024
#define H_ 16
#define DK_ 64
#define NTOK (B_*S_)

typedef __bf16 bf16;
typedef __bf16 bf16x8 __attribute__((ext_vector_type(8)));
typedef short s16x4 __attribute__((ext_vector_type(4)));
typedef float f32x4 __attribute__((ext_vector_type(4)));

#define AS1 __attribute__((address_space(1)))
#define AS3 __attribute__((address_space(3)))

static __device__ __forceinline__ short f2bf_s(float f) {
    return __builtin_bit_cast(short, (__bf16)f);
}

static __device__ __forceinline__ f32x4 mfma16(s16x4 a, s16x4 b, f32x4 c) {
#if __has_builtin(__builtin_amdgcn_mfma_f32_16x16x16bf16_1k)
    return __builtin_amdgcn_mfma_f32_16x16x16bf16_1k(a, b, c, 0, 0, 0);
#else
    asm volatile("v_mfma_f32_16x16x16_bf16 %0, %1, %2, %0\n\ts_nop 7\n\ts_nop 7"
                 : "+v"(c) : "v"(a), "v"(b));
    return c;
#endif
}

// ---------------- fused fp32 -> bf16 convert: [X | Wq | Wk | Wv | Wo] ----------------
__global__ void cvt_all(const float* __restrict__ x, const float* __restrict__ wq,
                        const float* __restrict__ wk, const float* __restrict__ wv,
                        const float* __restrict__ wo, bf16* __restrict__ dst) {
    const int NX8 = NTOK * D_ / 8;
    const int W8 = D_ * D_ / 8;          // 131072 = 2^17
    int i = blockIdx.x * blockDim.x + threadIdx.x;
    if (i >= NX8 + 4 * W8) return;
    const float* src; int j;
    if (i < NX8) { src = x; j = i; }
    else {
        int k = i - NX8;
        int w = k >> 17;
        j = k & (W8 - 1);
        src = w == 0 ? wq : (w == 1 ? wk : (w == 2 ? wv : wo));
    }
    const float4* s4 = reinterpret_cast<const float4*>(src) + (size_t)j * 2;
    float4 a = s4[0], b = s4[1];
    bf16x8 o;
    o[0] = (bf16)a.x; o[1] = (bf16)a.y; o[2] = (bf16)a.z; o[3] = (bf16)a.w;
    o[4] = (bf16)b.x; o[5] = (bf16)b.y; o[6] = (bf16)b.z; o[7] = (bf16)b.w;
    reinterpret_cast<bf16x8*>(dst)[i] = o;
}

// ---------------- RoPE cos/sin table: [NTOK][32] float2 ----------------
__global__ void rope_table(const int* __restrict__ pos, float2* __restrict__ tab) {
    int i = blockIdx.x * blockDim.x + threadIdx.x;
    if (i >= NTOK * 32) return;
    int n = i >> 5, p = i & 31;
    float pf = (float)pos[n];
    float freq = powf(10000.0f, -(float)p * (1.0f / 32.0f));
    float ang = pf * freq;
    float s, c;
    sincosf(ang, &s, &c);
    tab[i] = make_float2(c, s);
}

// ---------------- 128x128 GEMM, BK=64, counted-vmcnt, 2 blocks/CU ----------------
// 256 thr = 4 waves (2x2), per-wave C = 64x64. LDS 2 x 32KB = 64KB -> 2 blocks/CU
// co-resident (gemm256's 96KB allowed only 1 -> no cross-block overlap; this is
// the occupancy fix). Sync skeleton identical to verified R6 gemm256:
// BAR-A -> stage(kt+1) -> vmcnt(8 in flight) -> BAR-B. Chunk-XOR swizzle via
// pre-swizzled global source (rule #21), conflict-free verified in R6 (0 conflicts).
template<int MODE>
__global__ __launch_bounds__(256, 2)
void gemm128(const bf16* __restrict__ A, const bf16* __restrict__ Bw,
             void* __restrict__ OutP, const float2* __restrict__ tab) {
    const float SCL2E = 0.125f * 1.44269504088896340736f;
    constexpr int NKT = 16;                       // K/64
    __shared__ alignas(16) bf16 lds[2][(128 + 128) * 64];
    const int tid = threadIdx.x;
    const int lane = tid & 63;
    const int wid = tid >> 6;
    const int wm = wid >> 1;                      // 0..1
    const int wn = wid & 1;                       // 0..1
    const int lr = lane & 15, lg = lane >> 4;
    const int m0 = blockIdx.x * 128;
    const int n0g = blockIdx.y * 128;             // spans 3072 for QKV

    f32x4 acc[4][4] = {};

    // stage K-tile kt: A 128x64 (4 units) + B 128x64 (4 units), 16B/thread/unit
    auto stage = [&](int kt, int bufi) {
        bf16* dst = &lds[bufi][0];
#pragma unroll
        for (int j = 0; j < 4; ++j) {
            int flat = j * 256 + tid;
            int r = flat >> 3, c = flat & 7;
            const bf16* src = A + (size_t)(m0 + r) * 1024 + kt * 64 + ((c ^ (r & 7)) << 3);
            __builtin_amdgcn_global_load_lds((const AS1 uint32_t*)src,
                                             (AS3 uint32_t*)(dst + (size_t)flat * 8), 16, 0, 0);
        }
#pragma unroll
        for (int j = 0; j < 4; ++j) {
            int flat = j * 256 + tid;
            int r = flat >> 3, c = flat & 7;
            const bf16* src = Bw + (size_t)(n0g + r) * 1024 + kt * 64 + ((c ^ (r & 7)) << 3);
            __builtin_amdgcn_global_load_lds((const AS1 uint32_t*)src,
                                             (AS3 uint32_t*)(dst + 128 * 64 + (size_t)flat * 8), 16, 0, 0);
        }
    };

    stage(0, 0);

    for (int kt = 0; kt < NKT; ++kt) {
        const bf16* bufA = &lds[kt & 1][0];
        const bf16* bufB = bufA + 128 * 64;

        asm volatile("" ::: "memory");
        __builtin_amdgcn_s_barrier();             // BAR-A: reads of buf[(kt+1)&1] done
        asm volatile("" ::: "memory");
        if (kt + 1 < NKT) {
            stage(kt + 1, (kt + 1) & 1);
            asm volatile("s_waitcnt vmcnt(8)" ::: "memory");   // kt's 8 landed; 8 in flight
        } else {
            asm volatile("s_waitcnt vmcnt(0)" ::: "memory");
        }
        __builtin_amdgcn_s_barrier();             // BAR-B: buf[kt&1] valid
        asm volatile("" ::: "memory");

        const int sx = lr & 7;
        bf16x8 af[4][2], bfr[4][2];
#pragma unroll
        for (int mf = 0; mf < 4; ++mf)
#pragma unroll
            for (int kh = 0; kh < 2; ++kh)
                af[mf][kh] = *reinterpret_cast<const bf16x8*>(
                    &bufA[(wm * 64 + mf * 16 + lr) * 64 + (((kh * 4 + lg) ^ sx) << 3)]);
#pragma unroll
        for (int nf = 0; nf < 4; ++nf)
#pragma unroll
            for (int kh = 0; kh < 2; ++kh)
                bfr[nf][kh] = *reinterpret_cast<const bf16x8*>(
                    &bufB[(wn * 64 + nf * 16 + lr) * 64 + (((kh * 4 + lg) ^ sx) << 3)]);
        __builtin_amdgcn_s_setprio(1);
#pragma unroll
        for (int mf = 0; mf < 4; ++mf)
#pragma unroll
            for (int nf = 0; nf < 4; ++nf)
#pragma unroll
                for (int kh = 0; kh < 2; ++kh)
                    acc[mf][nf] = __builtin_amdgcn_mfma_f32_16x16x32_bf16(af[mf][kh], bfr[nf][kh], acc[mf][nf], 0, 0, 0);
        __builtin_amdgcn_s_setprio(0);
    }

    // epilogue: C layout col=lane&15, row=(lane>>4)*4+reg
#pragma unroll
    for (int mf = 0; mf < 4; ++mf) {
#pragma unroll
        for (int nf = 0; nf < 4; ++nf) {
#pragma unroll
            for (int r = 0; r < 4; ++r) {
                int row = m0 + wm * 64 + mf * 16 + lg * 4 + r;
                int colg = n0g + wn * 64 + nf * 16 + lr;
                float v = acc[mf][nf][r];
                if (MODE == 2) {
                    ((float*)OutP)[(size_t)row * 1024 + colg] = v;
                } else {
                    int which = colg >> 10;          // block-uniform
                    int col = colg & 1023;
                    bf16* O = (bf16*)OutP + (size_t)which * NTOK * D_;
                    if (which < 2) {
                        float partner = __shfl_xor(v, 1, 64);
                        float2 cs = tab[(size_t)row * 32 + ((col >> 1) & 31)];
                        float o = (col & 1) ? fmaf(v, cs.x, partner * cs.y)
                                            : fmaf(v, cs.x, -partner * cs.y);
                        if (which == 0) o *= SCL2E;
                        O[(size_t)row * D_ + col] = (bf16)o;
                    } else {
                        O[(size_t)row * D_ + col] = (bf16)v;
                    }
                }
            }
        }
    }
}

// ---------------- causal flash attention (exact R6-verified flash_attn5) ----------------
// grid (8, 64), 256 threads = 4 waves; strips qtA=bx, qtB=15-bx (perfect balance,
// 2 strip-computes per staged tile -> best measured: 100.7us). Do not restructure.
__global__ __launch_bounds__(256, 2)
void flash_attn5(const bf16* __restrict__ Q, const bf16* __restrict__ Kr,
                 const bf16* __restrict__ V, bf16* __restrict__ O) {
    __shared__ bf16 Ks[2][64 * 64];
    __shared__ bf16 Vt[2][64 * 64];
    const int tid = threadIdx.x, lane = tid & 63, w = tid >> 6;
    const int lr = lane & 15, lg = lane >> 4;
    const int qtA = blockIdx.x;
    const int qtB = 15 - qtA;
    const int q0[2] = { qtA * 128, qtB * 128 };
    const int ntS[2] = { 2 * qtA + 2, 2 * qtB + 2 };
    const int NT = ntS[1];
    const int bh = blockIdx.y;
    const int b = bh >> 4, h = bh & 15;
    const size_t base = ((size_t)b * S_) * D_ + (size_t)h * DK_;

    bf16x8 aq[2][2][2];
#pragma unroll
    for (int si = 0; si < 2; ++si)
#pragma unroll
        for (int qs = 0; qs < 2; ++qs) {
            int qrow = q0[si] + w * 32 + qs * 16 + lr;
            const bf16* qp = Q + base + (size_t)qrow * D_ + lg * 8;
            aq[si][qs][0] = *reinterpret_cast<const bf16x8*>(qp);
            aq[si][qs][1] = *reinterpret_cast<const bf16x8*>(qp + 32);
        }

    f32x4 acc[2][2][4] = {};
    float m_run[2][2] = {{-1e30f, -1e30f}, {-1e30f, -1e30f}};
    float l_run[2][2] = {{0.f, 0.f}, {0.f, 0.f}};

    const int sjj = tid >> 3;
    const int se0 = (tid & 7) * 8;
    const int vx = tid & 7;
    bf16x8 kreg[2], vreg[2];
#pragma unroll
    for (int i = 0; i < 2; ++i) {
        int row = sjj + i * 32;
        kreg[i] = *reinterpret_cast<const bf16x8*>(&Kr[base + (size_t)row * D_ + se0]);
        vreg[i] = *reinterpret_cast<const bf16x8*>(&V [base + (size_t)row * D_ + se0]);
    }

    for (int t = 0; t < NT; ++t) {
        const int j0 = t * 64;
        bf16* KsB = Ks[t & 1];
        bf16* VtB = Vt[t & 1];
#pragma unroll
        for (int i = 0; i < 2; ++i) {
            int jj = sjj + i * 32;
            *reinterpret_cast<bf16x8*>(&KsB[jj * 64 + (se0 ^ ((jj & 7) << 3))]) = kreg[i];
#pragma unroll
            for (int q = 0; q < 8; ++q) {
                int dd = se0 + q;
                int vswz = ((q ^ vx) & 7) << 3;
                VtB[dd * 64 + (jj ^ vswz)] = vreg[i][q];
            }
        }
        if (t + 1 < NT) {
#pragma unroll
            for (int i = 0; i < 2; ++i) {
                int row = (t + 1) * 64 + sjj + i * 32;
                kreg[i] = *reinterpret_cast<const bf16x8*>(&Kr[base + (size_t)row * D_ + se0]);
                vreg[i] = *reinterpret_cast<const bf16x8*>(&V [base + (size_t)row * D_ + se0]);
            }
        }
        __syncthreads();

#pragma unroll
        for (int si = 0; si < 2; ++si) {
            if (t >= ntS[si]) continue;
            const int qmaxw = q0[si] + w * 32 + 31;
            if (j0 > qmaxw) continue;

            f32x4 sc[2][4];
            __builtin_amdgcn_s_setprio(1);
#pragma unroll
            for (int nt = 0; nt < 4; ++nt) {
                int krow = nt * 16 + lr;
                int swz = (krow & 7) << 3;
                bf16x8 a0 = *reinterpret_cast<const bf16x8*>(&KsB[krow * 64 + ((lg * 8) ^ swz)]);
                bf16x8 a1 = *reinterpret_cast<const bf16x8*>(&KsB[krow * 64 + ((32 + lg * 8) ^ swz)]);
#pragma unroll
                for (int qs = 0; qs < 2; ++qs) {
                    f32x4 tv = {};
                    tv = __builtin_amdgcn_mfma_f32_16x16x32_bf16(a0, aq[si][qs][0], tv, 0, 0, 0);
                    tv = __builtin_amdgcn_mfma_f32_16x16x32_bf16(a1, aq[si][qs][1], tv, 0, 0, 0);
                    sc[qs][nt] = tv;
                }
            }
            __builtin_amdgcn_s_setprio(0);

            s16x4 ap[2][4];
#pragma unroll
            for (int qs = 0; qs < 2; ++qs) {
                const int qrow = q0[si] + w * 32 + qs * 16 + lr;
                if (j0 + 63 > q0[si] + w * 32 + qs * 16) {
#pragma unroll
                    for (int nt = 0; nt < 4; ++nt)
#pragma unroll
                        for (int r = 0; r < 4; ++r) {
                            int kv = j0 + nt * 16 + lg * 4 + r;
                            if (kv > qrow) sc[qs][nt][r] = -1e30f;
                        }
                }
                float tmax = sc[qs][0][0];
#pragma unroll
                for (int nt = 0; nt < 4; ++nt)
#pragma unroll
                    for (int r = 0; r < 4; ++r) tmax = fmaxf(tmax, sc[qs][nt][r]);
                tmax = fmaxf(tmax, __shfl_xor(tmax, 16, 64));
                tmax = fmaxf(tmax, __shfl_xor(tmax, 32, 64));
                float mold = m_run[si][qs];
                if (!__all(tmax - mold <= 8.0f)) {
                    float mnew = fmaxf(mold, tmax);
                    float corr = exp2f(mold - mnew);
                    m_run[si][qs] = mnew;
                    l_run[si][qs] *= corr;
#pragma unroll
                    for (int r = 0; r < 4; ++r) {
                        float cr = __shfl(corr, (lane & 48) | (lg * 4 + r), 64);
#pragma unroll
                        for (int dt = 0; dt < 4; ++dt) acc[si][qs][dt][r] *= cr;
                    }
                }
                float mnow = m_run[si][qs];
                float rs = 0.f;
#pragma unroll
                for (int nt = 0; nt < 4; ++nt)
#pragma unroll
                    for (int r = 0; r < 4; ++r) {
                        float p = exp2f(sc[qs][nt][r] - mnow);
                        rs += p;
                        ap[qs][nt][r] = f2bf_s(p);
                    }
                rs += __shfl_xor(rs, 16, 64);
                rs += __shfl_xor(rs, 32, 64);
                l_run[si][qs] += rs;
            }

            __builtin_amdgcn_s_setprio(1);
#pragma unroll
            for (int dt = 0; dt < 4; ++dt) {
                int vrow = dt * 16 + lr;
                int vswz = (((vrow & 7) ^ (vrow >> 3)) & 7) << 3;
                s16x4 bv[4];
#pragma unroll
                for (int nt = 0; nt < 4; ++nt)
                    bv[nt] = *reinterpret_cast<const s16x4*>(&VtB[vrow * 64 + ((nt * 16 + lg * 4) ^ vswz)]);
#pragma unroll
                for (int qs = 0; qs < 2; ++qs)
#pragma unroll
                    for (int nt = 0; nt < 4; ++nt)
                        acc[si][qs][dt] = mfma16(ap[qs][nt], bv[nt], acc[si][qs][dt]);
            }
            __builtin_amdgcn_s_setprio(0);
        }
    }

#pragma unroll
    for (int si = 0; si < 2; ++si)
#pragma unroll
        for (int qs = 0; qs < 2; ++qs) {
            float inv = __builtin_amdgcn_rcpf(l_run[si][qs]);
#pragma unroll
            for (int r = 0; r < 4; ++r) {
                float invr = __shfl(inv, (lane & 48) | (lg * 4 + r), 64);
                int row = q0[si] + w * 32 + qs * 16 + lg * 4 + r;
#pragma unroll
                for (int dt = 0; dt < 4; ++dt)
                    O[base + (size_t)row * D_ + dt * 16 + lr] = (bf16)(acc[si][qs][dt][r] * invr);
            }
        }
}

// ---------------- launcher ----------------
extern "C" void kernel_launch(void* const* d_in, const int* in_sizes, int n_in,
                              void* d_out, int out_size, void* d_ws, size_t ws_size,
                              hipStream_t stream) {
    const float* x  = (const float*)d_in[0];
    const int*   tp = (const int*)d_in[1];
    const float* wq = (const float*)d_in[2];
    const float* wk = (const float*)d_in[3];
    const float* wv = (const float*)d_in[4];
    const float* wo = (const float*)d_in[5];

    bf16* ws = (bf16*)d_ws;
    bf16* Xbf = ws;
    bf16* Wqb = Xbf + (size_t)NTOK * D_;          // [3072][1024] packed Wq|Wk|Wv
    bf16* Wkb = Wqb + (size_t)D_ * D_;
    bf16* Wvb = Wkb + (size_t)D_ * D_;
    bf16* Wob = Wvb + (size_t)D_ * D_;
    bf16* Qr  = Wob + (size_t)D_ * D_;
    bf16* Kb  = Qr + (size_t)NTOK * D_;
    bf16* Vb  = Kb + (size_t)NTOK * D_;
    bf16* AO  = Vb + (size_t)NTOK * D_;
    float2* tab = (float2*)(AO + (size_t)NTOK * D_);
    (void)ws_size; (void)in_sizes; (void)n_in; (void)out_size;
    (void)Wkb; (void)Wvb;

    {
        int ntot8 = (NTOK * D_ + 4 * D_ * D_) / 8;
        cvt_all<<<(ntot8 + 255) / 256, 256, 0, stream>>>(x, wq, wk, wv, wo, Xbf);
    }
    rope_table<<<(NTOK * 32 + 255) / 256, 256, 0, stream>>>(tp, tab);

    // QKV: one GEMM vs packed [3072][1024] weights; grid 64x24 = 1536 blocks
    gemm128<1><<<dim3(NTOK / 128, 24), 256, 0, stream>>>(Xbf, Wqb, Qr, tab);

    flash_attn5<<<dim3(8, B_ * H_), 256, 0, stream>>>(Qr, Kb, Vb, AO);

    // out-projection: grid 64x8 = 512 blocks, fp32 out
    gemm128<2><<<dim3(NTOK / 128, D_ / 128), 256, 0, stream>>>(AO, Wob, d_out, nullptr);
}